// Round 5
// baseline (555.872 us; speedup 1.0000x reference)
//
#include <hip/hip_runtime.h>

// Wilson Dslash, 32^4 lattice, DeGrand-Rossi basis, separate re/im fp32 planes.
// res(x) = -0.5 * sum_mu [ (I-g_mu) U_mu(x) psi(x+mu) + (I+g_mu) U_mu(x-mu)^dag psi(x-mu) ]
//
// R3 (kept): full forward-U record fetched contiguously once per site.
// R4 (kept): XCD-patch block mapping; all z/t/y reuse L2-captured (FETCH 687MB,
//            residual = x-halo, structural: 2 x-slices+U > 4MB L2).
// R5: BW efficiency is now the binder (3.39 of 6.3 TB/s, occupancy 20.8% -- LDS
// 304B/thread caps 8 waves/CU). Halve the slot: chunks mu=2,3 stay in REGISTERS
// and are consumed by the first two (statically-unrolled) phases; only mu=0,1 go
// to LDS (41-dword slot = 164B/thread -> 7 blocks/CU = 14 waves/CU). The mu=1,0
// phases run in a #pragma unroll 1 rolled loop (R2-proven low-pressure pattern)
// reading U from LDS at runtime-mu offsets. Odd slot stride (41) spreads banks
// -> kills the stride-76 8-way conflicts (1.1e7 -> ~0).

static constexpr int SITES = 32 * 32 * 32 * 32;

__device__ __forceinline__ void load12(const float* __restrict__ p, float* v) {
    const float4* q = reinterpret_cast<const float4*>(p);  // site*12 floats = 48B, 16B-aligned
    float4 a = q[0], b = q[1], c = q[2];
    v[0] = a.x; v[1] = a.y; v[2]  = a.z; v[3]  = a.w;
    v[4] = b.x; v[5] = b.y; v[6]  = b.z; v[7]  = b.w;
    v[8] = c.x; v[9] = c.y; v[10] = c.z; v[11] = c.w;
}

// g[s][i] = sum_j U[i][j] h[s][j]  (complex, U row-major 9)
__device__ __forceinline__ void mulU(const float* ur, const float* ui,
                                     const float* hr, const float* hi,
                                     float* gr, float* gi) {
#pragma unroll
    for (int s = 0; s < 2; ++s)
#pragma unroll
        for (int i = 0; i < 3; ++i) {
            float rr = 0.f, im = 0.f;
#pragma unroll
            for (int j = 0; j < 3; ++j) {
                const float a = ur[i * 3 + j], b = ui[i * 3 + j];
                rr += a * hr[s * 3 + j] - b * hi[s * 3 + j];
                im += a * hi[s * 3 + j] + b * hr[s * 3 + j];
            }
            gr[s * 3 + i] = rr; gi[s * 3 + i] = im;
        }
}

// g[s][i] = sum_j conj(U[j][i]) h[s][j]
__device__ __forceinline__ void mulUdag(const float* ur, const float* ui,
                                        const float* hr, const float* hi,
                                        float* gr, float* gi) {
#pragma unroll
    for (int s = 0; s < 2; ++s)
#pragma unroll
        for (int i = 0; i < 3; ++i) {
            float rr = 0.f, im = 0.f;
#pragma unroll
            for (int j = 0; j < 3; ++j) {
                const float a = ur[j * 3 + i], b = ui[j * 3 + i];
                rr += a * hr[s * 3 + j] + b * hi[s * 3 + j];
                im += a * hi[s * 3 + j] - b * hr[s * 3 + j];
            }
            gr[s * 3 + i] = rr; gi[s * 3 + i] = im;
        }
}

// One full mu-phase (forward + backward hop), MU compile-time (register-U phases).
template<int MU>
__device__ __forceinline__ void phase_static(
    int site,
    const float* __restrict__ psi_re, const float* __restrict__ psi_im,
    const float* __restrict__ U_re,   const float* __restrict__ U_im,
    const float* ufr, const float* ufi,   // forward-U chunk (registers)
    float* ar, float* ai)
{
    const int sh  = 15 - 5 * MU;
    const int S   = 1 << sh;
    const int cmu = (site >> sh) & 31;
    const int nf  = site + (cmu == 31 ? -31 * S : S);
    const int nb  = site + (cmu == 0  ?  31 * S : -S);

    float vr[12], vi[12], hr[6], hi[6], gr[6], gi[6];

    // ---- forward: (I - g_mu) U_mu(x) psi(x+mu)
    load12(psi_re + (size_t)nf * 12, vr);
    load12(psi_im + (size_t)nf * 12, vi);
#pragma unroll
    for (int c = 0; c < 3; ++c) {
        if constexpr (MU == 2) {        // h0 = v0 - i v2 ; h1 = v1 + i v3
            hr[c]     = vr[c]     + vi[6 + c];  hi[c]     = vi[c]     - vr[6 + c];
            hr[3 + c] = vr[3 + c] - vi[9 + c];  hi[3 + c] = vi[3 + c] + vr[9 + c];
        } else {                        // MU == 3: h0 = v0 - v2 ; h1 = v1 - v3
            hr[c]     = vr[c]     - vr[6 + c];  hi[c]     = vi[c]     - vi[6 + c];
            hr[3 + c] = vr[3 + c] - vr[9 + c];  hi[3 + c] = vi[3 + c] - vi[9 + c];
        }
    }
    mulU(ufr, ufi, hr, hi, gr, gi);
#pragma unroll
    for (int c = 0; c < 3; ++c) {
        ar[c]     += gr[c];      ai[c]     += gi[c];
        ar[3 + c] += gr[3 + c];  ai[3 + c] += gi[3 + c];
        if constexpr (MU == 2) {        // r2 += i g0 ; r3 += -i g1
            ar[6 + c] -= gi[c];      ai[6 + c] += gr[c];
            ar[9 + c] += gi[3 + c];  ai[9 + c] -= gr[3 + c];
        } else {                        // r2 += -g0 ; r3 += -g1
            ar[6 + c] -= gr[c];      ai[6 + c] -= gi[c];
            ar[9 + c] -= gr[3 + c];  ai[9 + c] -= gi[3 + c];
        }
    }

    // ---- backward: (I + g_mu) U_mu(x-mu)^dag psi(x-mu)
    load12(psi_re + (size_t)nb * 12, vr);
    load12(psi_im + (size_t)nb * 12, vi);
    float ur[9], ui[9];
    {
        // Neighbor's record chunk: z/t neighbors are (mostly) in-block -> L1/L2 hit.
        const float* pur = U_re + ((size_t)nb * 4 + MU) * 9;
        const float* pui = U_im + ((size_t)nb * 4 + MU) * 9;
#pragma unroll
        for (int k = 0; k < 9; ++k) { ur[k] = pur[k]; ui[k] = pui[k]; }
    }
#pragma unroll
    for (int c = 0; c < 3; ++c) {
        if constexpr (MU == 2) {        // h0 = v0 + i v2 ; h1 = v1 - i v3
            hr[c]     = vr[c]     - vi[6 + c];  hi[c]     = vi[c]     + vr[6 + c];
            hr[3 + c] = vr[3 + c] + vi[9 + c];  hi[3 + c] = vi[3 + c] - vr[9 + c];
        } else {                        // h0 = v0 + v2 ; h1 = v1 + v3
            hr[c]     = vr[c]     + vr[6 + c];  hi[c]     = vi[c]     + vi[6 + c];
            hr[3 + c] = vr[3 + c] + vr[9 + c];  hi[3 + c] = vi[3 + c] + vi[9 + c];
        }
    }
    mulUdag(ur, ui, hr, hi, gr, gi);
#pragma unroll
    for (int c = 0; c < 3; ++c) {
        ar[c]     += gr[c];      ai[c]     += gi[c];
        ar[3 + c] += gr[3 + c];  ai[3 + c] += gi[3 + c];
        if constexpr (MU == 2) {        // r2 += -i g0 ; r3 += i g1
            ar[6 + c] += gi[c];      ai[6 + c] -= gr[c];
            ar[9 + c] -= gi[3 + c];  ai[9 + c] += gr[3 + c];
        } else {                        // r2 += g0 ; r3 += g1
            ar[6 + c] += gr[c];      ai[6 + c] += gi[c];
            ar[9 + c] += gr[3 + c];  ai[9 + c] += gi[3 + c];
        }
    }
}

__global__ __launch_bounds__(128) void wilson_dslash_kernel(
    const float* __restrict__ psi_re, const float* __restrict__ psi_im,
    const float* __restrict__ U_re,   const float* __restrict__ U_im,
    float* __restrict__ out_re,       float* __restrict__ out_im)
{
    // R4 mapping: 8192 blocks = 8 XCDs x 1024; XCD c owns a 16x8 (x,y) patch,
    // dispatch order zq fastest, then y, then x.
    const int cxcd = blockIdx.x & 7;
    const int r    = blockIdx.x >> 3;     // [0,1024)
    const int xl   = r >> 6;              // [0,16)
    const int rem  = r & 63;
    const int yl   = rem >> 3;            // [0,8)
    const int zq   = rem & 7;             // [0,8)
    const int x    = ((cxcd & 1) << 4) | xl;
    const int y    = ((cxcd >> 1) << 3) | yl;
    const int tid  = threadIdx.x;
    const int site = (x << 15) | (y << 10) | (zq << 7) | tid;  // z=zq*4+tid/32, t=tid%32

    // LDS slot: chunks mu=0,1 only. Layout: [mu0 re 0..8][mu1 re 9..17]
    // [mu0 im 18..26][mu1 im 27..35], stride 41 dwords (odd -> bank-spread).
    __shared__ float uf[128 * 41];
    float* slot = &uf[tid * 41];

    float u2r[9], u2i[9], u3r[9], u3i[9];   // chunks mu=2,3 held in registers
    {
        float fre[36], fim[36];
        const float4* pr = reinterpret_cast<const float4*>(U_re + (size_t)site * 36);
        const float4* pi = reinterpret_cast<const float4*>(U_im + (size_t)site * 36);
#pragma unroll
        for (int k = 0; k < 9; ++k) {
            float4 a = pr[k], b = pi[k];
            fre[4 * k + 0] = a.x; fre[4 * k + 1] = a.y; fre[4 * k + 2] = a.z; fre[4 * k + 3] = a.w;
            fim[4 * k + 0] = b.x; fim[4 * k + 1] = b.y; fim[4 * k + 2] = b.z; fim[4 * k + 3] = b.w;
        }
#pragma unroll
        for (int k = 0; k < 18; ++k) { slot[k] = fre[k]; slot[18 + k] = fim[k]; }
#pragma unroll
        for (int k = 0; k < 9; ++k) {
            u2r[k] = fre[18 + k]; u2i[k] = fim[18 + k];
            u3r[k] = fre[27 + k]; u3i[k] = fim[27 + k];
        }
    }

    float ar[12], ai[12];
#pragma unroll
    for (int k = 0; k < 12; ++k) { ar[k] = 0.f; ai[k] = 0.f; }

    // Register-U phases first (their U regs die here).
    phase_static<3>(site, psi_re, psi_im, U_re, U_im, u3r, u3i, ar, ai);
    phase_static<2>(site, psi_re, psi_im, U_re, U_im, u2r, u2i, ar, ai);

    // LDS-U phases: rolled loop (low register pressure), runtime-mu LDS offsets.
#pragma unroll 1
    for (int mu = 1; mu >= 0; --mu) {
        const int sh  = 15 - 5 * mu;
        const int S   = 1 << sh;
        const int cmu = (site >> sh) & 31;
        const int nf  = site + (cmu == 31 ? -31 * S : S);
        const int nb  = site + (cmu == 0  ?  31 * S : -S);
        const float* ufr = slot + mu * 9;        // mu0 re @0, mu1 re @9
        const float* ufi = slot + 18 + mu * 9;   // mu0 im @18, mu1 im @27

        float vr[12], vi[12], hr[6], hi[6], gr[6], gi[6];

        // ---- forward
        load12(psi_re + (size_t)nf * 12, vr);
        load12(psi_im + (size_t)nf * 12, vi);
        if (mu == 0) {          // h0 = v0 - i v3 ; h1 = v1 - i v2
#pragma unroll
            for (int c = 0; c < 3; ++c) {
                hr[c]     = vr[c]     + vi[9 + c];  hi[c]     = vi[c]     - vr[9 + c];
                hr[3 + c] = vr[3 + c] + vi[6 + c];  hi[3 + c] = vi[3 + c] - vr[6 + c];
            }
        } else {                // h0 = v0 + v3 ; h1 = v1 - v2
#pragma unroll
            for (int c = 0; c < 3; ++c) {
                hr[c]     = vr[c]     + vr[9 + c];  hi[c]     = vi[c]     + vi[9 + c];
                hr[3 + c] = vr[3 + c] - vr[6 + c];  hi[3 + c] = vi[3 + c] - vi[6 + c];
            }
        }
        mulU(ufr, ufi, hr, hi, gr, gi);
#pragma unroll
        for (int c = 0; c < 3; ++c) {
            ar[c]     += gr[c];      ai[c]     += gi[c];
            ar[3 + c] += gr[3 + c];  ai[3 + c] += gi[3 + c];
        }
        if (mu == 0) {          // r2 += i g1 ; r3 += i g0
#pragma unroll
            for (int c = 0; c < 3; ++c) {
                ar[6 + c] -= gi[3 + c];  ai[6 + c] += gr[3 + c];
                ar[9 + c] -= gi[c];      ai[9 + c] += gr[c];
            }
        } else {                // r2 += -g1 ; r3 += g0
#pragma unroll
            for (int c = 0; c < 3; ++c) {
                ar[6 + c] -= gr[3 + c];  ai[6 + c] -= gi[3 + c];
                ar[9 + c] += gr[c];      ai[9 + c] += gi[c];
            }
        }

        // ---- backward
        load12(psi_re + (size_t)nb * 12, vr);
        load12(psi_im + (size_t)nb * 12, vi);
        float ur[9], ui[9];
        {
            // Neighbor block's record (y: 8 blocks back -> L2 hit; x: 64 back -> miss)
            const float* pur = U_re + ((size_t)nb * 4 + mu) * 9;
            const float* pui = U_im + ((size_t)nb * 4 + mu) * 9;
#pragma unroll
            for (int k = 0; k < 9; ++k) { ur[k] = pur[k]; ui[k] = pui[k]; }
        }
        if (mu == 0) {          // h0 = v0 + i v3 ; h1 = v1 + i v2
#pragma unroll
            for (int c = 0; c < 3; ++c) {
                hr[c]     = vr[c]     - vi[9 + c];  hi[c]     = vi[c]     + vr[9 + c];
                hr[3 + c] = vr[3 + c] - vi[6 + c];  hi[3 + c] = vi[3 + c] + vr[6 + c];
            }
        } else {                // h0 = v0 - v3 ; h1 = v1 + v2
#pragma unroll
            for (int c = 0; c < 3; ++c) {
                hr[c]     = vr[c]     - vr[9 + c];  hi[c]     = vi[c]     - vi[9 + c];
                hr[3 + c] = vr[3 + c] + vr[6 + c];  hi[3 + c] = vi[3 + c] + vi[6 + c];
            }
        }
        mulUdag(ur, ui, hr, hi, gr, gi);
#pragma unroll
        for (int c = 0; c < 3; ++c) {
            ar[c]     += gr[c];      ai[c]     += gi[c];
            ar[3 + c] += gr[3 + c];  ai[3 + c] += gi[3 + c];
        }
        if (mu == 0) {          // r2 += -i g1 ; r3 += -i g0
#pragma unroll
            for (int c = 0; c < 3; ++c) {
                ar[6 + c] += gi[3 + c];  ai[6 + c] -= gr[3 + c];
                ar[9 + c] += gi[c];      ai[9 + c] -= gr[c];
            }
        } else {                // r2 += g1 ; r3 += -g0
#pragma unroll
            for (int c = 0; c < 3; ++c) {
                ar[6 + c] += gr[3 + c];  ai[6 + c] += gi[3 + c];
                ar[9 + c] -= gr[c];      ai[9 + c] -= gi[c];
            }
        }
    }

    // out = -0.5 * acc, vectorized stores
    float4* orp = reinterpret_cast<float4*>(out_re + (size_t)site * 12);
    float4* oip = reinterpret_cast<float4*>(out_im + (size_t)site * 12);
    orp[0] = make_float4(-0.5f * ar[0], -0.5f * ar[1], -0.5f * ar[2],  -0.5f * ar[3]);
    orp[1] = make_float4(-0.5f * ar[4], -0.5f * ar[5], -0.5f * ar[6],  -0.5f * ar[7]);
    orp[2] = make_float4(-0.5f * ar[8], -0.5f * ar[9], -0.5f * ar[10], -0.5f * ar[11]);
    oip[0] = make_float4(-0.5f * ai[0], -0.5f * ai[1], -0.5f * ai[2],  -0.5f * ai[3]);
    oip[1] = make_float4(-0.5f * ai[4], -0.5f * ai[5], -0.5f * ai[6],  -0.5f * ai[7]);
    oip[2] = make_float4(-0.5f * ai[8], -0.5f * ai[9], -0.5f * ai[10], -0.5f * ai[11]);
}

extern "C" void kernel_launch(void* const* d_in, const int* in_sizes, int n_in,
                              void* d_out, int out_size, void* d_ws, size_t ws_size,
                              hipStream_t stream) {
    const float* psi_re = (const float*)d_in[0];
    const float* psi_im = (const float*)d_in[1];
    const float* U_re   = (const float*)d_in[2];
    const float* U_im   = (const float*)d_in[3];
    // d_in[4..7] are the projector matrices; hardcoded in-kernel.
    float* out_re = (float*)d_out;
    float* out_im = out_re + (size_t)SITES * 12;

    wilson_dslash_kernel<<<SITES / 128, 128, 0, stream>>>(
        psi_re, psi_im, U_re, U_im, out_re, out_im);
}

// Round 6
// 516.370 us; speedup vs baseline: 1.0765x; 1.0765x over previous
//
#include <hip/hip_runtime.h>

// Wilson Dslash, 32^4 lattice, DeGrand-Rossi basis, separate re/im fp32 planes.
// res(x) = -0.5 * sum_mu [ (I-g_mu) U_mu(x) psi(x+mu) + (I+g_mu) U_mu(x-mu)^dag psi(x-mu) ]
// Spin-projection trick: project to 2 half-spinors, color-multiply only those,
// reconstruct lower spin rows with fixed per-mu phases.
//
// R3 (kept): per-thread LDS staging of the full forward-U record (one contiguous
// fetch per record; runtime-mu chunk reads from LDS).
// R4 (kept): XCD-patch block mapping (16x8 (x,y) patch per XCD).
// R5 (REVERTED): split static/rolled phases + smaller LDS slot regressed 238->300us
// (occupancy never rose -- LDS wasn't the binder -- and FETCH went +11%).
// R6: dispatch-order swap ONLY, on the exact R4 body: xl fastest (was zq), yl,
// then zq slowest. x+-1 neighbor blocks now 1 apart in dispatch -> psi x-halo and
// backward-U(x-1) become L2 hits (was the ~280MB residual); y gap becomes 16
// blocks (~2.7MB stream < 4MB L2, still hits); new cost is z quad-edge only
// (~70MB). Pure locality A/B vs R4.

static constexpr int SITES = 32 * 32 * 32 * 32;

__device__ __forceinline__ void load12(const float* __restrict__ p, float* v) {
    const float4* q = reinterpret_cast<const float4*>(p);  // site*12 floats = 48B, 16B-aligned
    float4 a = q[0], b = q[1], c = q[2];
    v[0] = a.x; v[1] = a.y; v[2]  = a.z; v[3]  = a.w;
    v[4] = b.x; v[5] = b.y; v[6]  = b.z; v[7]  = b.w;
    v[8] = c.x; v[9] = c.y; v[10] = c.z; v[11] = c.w;
}

__global__ __launch_bounds__(128) void wilson_dslash_kernel(
    const float* __restrict__ psi_re, const float* __restrict__ psi_im,
    const float* __restrict__ U_re,   const float* __restrict__ U_im,
    float* __restrict__ out_re,       float* __restrict__ out_im)
{
    // 8192 blocks = 8 XCDs x 1024. XCD c = blockIdx&7 owns a 16x8 (x,y) patch.
    // Within the patch, dispatch order: xl fastest, then yl, then zq (R6 swap).
    const int cxcd = blockIdx.x & 7;
    const int r    = blockIdx.x >> 3;     // [0,1024)
    const int zq   = r >> 7;              // [0,8)   slowest
    const int yl   = (r >> 4) & 7;        // [0,8)
    const int xl   = r & 15;              // [0,16)  fastest
    const int x    = ((cxcd & 1) << 4) | xl;
    const int y    = ((cxcd >> 1) << 3) | yl;
    const int tid  = threadIdx.x;
    const int site = (x << 15) | (y << 10) | (zq << 7) | tid;  // z = zq*4 + tid/32, t = tid%32

    // Per-thread LDS slot: [re 36][pad 4][im 36] dwords, stride 76 (304B, 16B-aligned).
    __shared__ float uf[128 * 76];
    float* myu = &uf[tid * 76];
    {
        const float4* pr = reinterpret_cast<const float4*>(U_re + (size_t)site * 36);
        const float4* pi = reinterpret_cast<const float4*>(U_im + (size_t)site * 36);
        float4* dr = reinterpret_cast<float4*>(myu);        // tid*304B, 16B-aligned
        float4* di = reinterpret_cast<float4*>(myu + 40);   // +160B, 16B-aligned
#pragma unroll
        for (int k = 0; k < 9; ++k) { dr[k] = pr[k]; di[k] = pi[k]; }
    }

    float ar[12], ai[12];   // accumulator, index = spin*3 + color
#pragma unroll
    for (int k = 0; k < 12; ++k) { ar[k] = 0.f; ai[k] = 0.f; }

#pragma unroll 1
    for (int mu = 0; mu < 4; ++mu) {
        const int sh  = 15 - 5 * mu;          // stride = 2^sh: x=15, y=10, z=5, t=0
        const int S   = 1 << sh;
        const int cmu = (site >> sh) & 31;
        const int nf  = site + (cmu == 31 ? -31 * S : S);   // x + mu (periodic)
        const int nb  = site + (cmu == 0  ?  31 * S : -S);  // x - mu (periodic)

        float vr[12], vi[12];
        float hr[6], hi[6];   // half-spinor, index = s*3 + color
        float gr[6], gi[6];

        // ================= forward hop: (I - g_mu) U_mu(x) psi(x+mu) =================
        load12(psi_re + (size_t)nf * 12, vr);
        load12(psi_im + (size_t)nf * 12, vi);
        const float* urp = myu + mu * 9;        // LDS, dynamic mu index OK
        const float* uip = myu + 40 + mu * 9;
        if (mu == 0) {          // h0 = v0 - i v3 ; h1 = v1 - i v2
#pragma unroll
            for (int c2 = 0; c2 < 3; ++c2) {
                hr[c2]     = vr[c2]     + vi[9 + c2];  hi[c2]     = vi[c2]     - vr[9 + c2];
                hr[3 + c2] = vr[3 + c2] + vi[6 + c2];  hi[3 + c2] = vi[3 + c2] - vr[6 + c2];
            }
        } else if (mu == 1) {   // h0 = v0 + v3 ; h1 = v1 - v2
#pragma unroll
            for (int c2 = 0; c2 < 3; ++c2) {
                hr[c2]     = vr[c2]     + vr[9 + c2];  hi[c2]     = vi[c2]     + vi[9 + c2];
                hr[3 + c2] = vr[3 + c2] - vr[6 + c2];  hi[3 + c2] = vi[3 + c2] - vi[6 + c2];
            }
        } else if (mu == 2) {   // h0 = v0 - i v2 ; h1 = v1 + i v3
#pragma unroll
            for (int c2 = 0; c2 < 3; ++c2) {
                hr[c2]     = vr[c2]     + vi[6 + c2];  hi[c2]     = vi[c2]     - vr[6 + c2];
                hr[3 + c2] = vr[3 + c2] - vi[9 + c2];  hi[3 + c2] = vi[3 + c2] + vr[9 + c2];
            }
        } else {                // h0 = v0 - v2 ; h1 = v1 - v3
#pragma unroll
            for (int c2 = 0; c2 < 3; ++c2) {
                hr[c2]     = vr[c2]     - vr[6 + c2];  hi[c2]     = vi[c2]     - vi[6 + c2];
                hr[3 + c2] = vr[3 + c2] - vr[9 + c2];  hi[3 + c2] = vi[3 + c2] - vi[9 + c2];
            }
        }
        // g[s][i] = sum_j U[i][j] h[s][j]   (complex), U from LDS
#pragma unroll
        for (int s = 0; s < 2; ++s)
#pragma unroll
            for (int i = 0; i < 3; ++i) {
                float rr = 0.f, im = 0.f;
#pragma unroll
                for (int j = 0; j < 3; ++j) {
                    const float a = urp[i * 3 + j], b = uip[i * 3 + j];
                    rr += a * hr[s * 3 + j] - b * hi[s * 3 + j];
                    im += a * hi[s * 3 + j] + b * hr[s * 3 + j];
                }
                gr[s * 3 + i] = rr; gi[s * 3 + i] = im;
            }
        // reconstruct: rows 0,1 += g0,g1 always; rows 2,3 per mu
#pragma unroll
        for (int c2 = 0; c2 < 3; ++c2) {
            ar[c2]     += gr[c2];      ai[c2]     += gi[c2];
            ar[3 + c2] += gr[3 + c2];  ai[3 + c2] += gi[3 + c2];
        }
        if (mu == 0) {          // r2 += i g1 ; r3 += i g0
#pragma unroll
            for (int c2 = 0; c2 < 3; ++c2) {
                ar[6 + c2] -= gi[3 + c2];  ai[6 + c2] += gr[3 + c2];
                ar[9 + c2] -= gi[c2];      ai[9 + c2] += gr[c2];
            }
        } else if (mu == 1) {   // r2 += -g1 ; r3 += g0
#pragma unroll
            for (int c2 = 0; c2 < 3; ++c2) {
                ar[6 + c2] -= gr[3 + c2];  ai[6 + c2] -= gi[3 + c2];
                ar[9 + c2] += gr[c2];      ai[9 + c2] += gi[c2];
            }
        } else if (mu == 2) {   // r2 += i g0 ; r3 += -i g1
#pragma unroll
            for (int c2 = 0; c2 < 3; ++c2) {
                ar[6 + c2] -= gi[c2];      ai[6 + c2] += gr[c2];
                ar[9 + c2] += gi[3 + c2];  ai[9 + c2] -= gr[3 + c2];
            }
        } else {                // r2 += -g0 ; r3 += -g1
#pragma unroll
            for (int c2 = 0; c2 < 3; ++c2) {
                ar[6 + c2] -= gr[c2];      ai[6 + c2] -= gi[c2];
                ar[9 + c2] -= gr[3 + c2];  ai[9 + c2] -= gi[3 + c2];
            }
        }

        // ================= backward hop: (I + g_mu) U_mu(x-mu)^dag psi(x-mu) =================
        load12(psi_re + (size_t)nb * 12, vr);
        load12(psi_im + (size_t)nb * 12, vi);
        float ur[9], ui[9];
        {
            // Aliases a neighbor block's staged record: x-1 is now the previous
            // block in dispatch (L2 hit); y-1 16 blocks back (L2); z/t in-block (L1).
            const float* pur = U_re + ((size_t)nb * 4 + mu) * 9;
            const float* pui = U_im + ((size_t)nb * 4 + mu) * 9;
#pragma unroll
            for (int k = 0; k < 9; ++k) { ur[k] = pur[k]; ui[k] = pui[k]; }
        }
        if (mu == 0) {          // h0 = v0 + i v3 ; h1 = v1 + i v2
#pragma unroll
            for (int c2 = 0; c2 < 3; ++c2) {
                hr[c2]     = vr[c2]     - vi[9 + c2];  hi[c2]     = vi[c2]     + vr[9 + c2];
                hr[3 + c2] = vr[3 + c2] - vi[6 + c2];  hi[3 + c2] = vi[3 + c2] + vr[6 + c2];
            }
        } else if (mu == 1) {   // h0 = v0 - v3 ; h1 = v1 + v2
#pragma unroll
            for (int c2 = 0; c2 < 3; ++c2) {
                hr[c2]     = vr[c2]     - vr[9 + c2];  hi[c2]     = vi[c2]     - vi[9 + c2];
                hr[3 + c2] = vr[3 + c2] + vr[6 + c2];  hi[3 + c2] = vi[3 + c2] + vi[6 + c2];
            }
        } else if (mu == 2) {   // h0 = v0 + i v2 ; h1 = v1 - i v3
#pragma unroll
            for (int c2 = 0; c2 < 3; ++c2) {
                hr[c2]     = vr[c2]     - vi[6 + c2];  hi[c2]     = vi[c2]     + vr[6 + c2];
                hr[3 + c2] = vr[3 + c2] + vi[9 + c2];  hi[3 + c2] = vi[3 + c2] - vr[9 + c2];
            }
        } else {                // h0 = v0 + v2 ; h1 = v1 + v3
#pragma unroll
            for (int c2 = 0; c2 < 3; ++c2) {
                hr[c2]     = vr[c2]     + vr[6 + c2];  hi[c2]     = vi[c2]     + vi[6 + c2];
                hr[3 + c2] = vr[3 + c2] + vr[9 + c2];  hi[3 + c2] = vi[3 + c2] + vi[9 + c2];
            }
        }
        // g[s][i] = sum_j conj(U[j][i]) h[s][j]
#pragma unroll
        for (int s = 0; s < 2; ++s)
#pragma unroll
            for (int i = 0; i < 3; ++i) {
                float rr = 0.f, im = 0.f;
#pragma unroll
                for (int j = 0; j < 3; ++j) {
                    rr += ur[j * 3 + i] * hr[s * 3 + j] + ui[j * 3 + i] * hi[s * 3 + j];
                    im += ur[j * 3 + i] * hi[s * 3 + j] - ui[j * 3 + i] * hr[s * 3 + j];
                }
                gr[s * 3 + i] = rr; gi[s * 3 + i] = im;
            }
#pragma unroll
        for (int c2 = 0; c2 < 3; ++c2) {
            ar[c2]     += gr[c2];      ai[c2]     += gi[c2];
            ar[3 + c2] += gr[3 + c2];  ai[3 + c2] += gi[3 + c2];
        }
        if (mu == 0) {          // r2 += -i g1 ; r3 += -i g0
#pragma unroll
            for (int c2 = 0; c2 < 3; ++c2) {
                ar[6 + c2] += gi[3 + c2];  ai[6 + c2] -= gr[3 + c2];
                ar[9 + c2] += gi[c2];      ai[9 + c2] -= gr[c2];
            }
        } else if (mu == 1) {   // r2 += g1 ; r3 += -g0
#pragma unroll
            for (int c2 = 0; c2 < 3; ++c2) {
                ar[6 + c2] += gr[3 + c2];  ai[6 + c2] += gi[3 + c2];
                ar[9 + c2] -= gr[c2];      ai[9 + c2] -= gi[c2];
            }
        } else if (mu == 2) {   // r2 += -i g0 ; r3 += i g1
#pragma unroll
            for (int c2 = 0; c2 < 3; ++c2) {
                ar[6 + c2] += gi[c2];      ai[6 + c2] -= gr[c2];
                ar[9 + c2] -= gi[3 + c2];  ai[9 + c2] += gr[3 + c2];
            }
        } else {                // r2 += g0 ; r3 += g1
#pragma unroll
            for (int c2 = 0; c2 < 3; ++c2) {
                ar[6 + c2] += gr[c2];      ai[6 + c2] += gi[c2];
                ar[9 + c2] += gr[3 + c2];  ai[9 + c2] += gi[3 + c2];
            }
        }
    }

    // out = -0.5 * acc, vectorized stores (sites contiguous within a block)
    float4* orp = reinterpret_cast<float4*>(out_re + (size_t)site * 12);
    float4* oip = reinterpret_cast<float4*>(out_im + (size_t)site * 12);
    orp[0] = make_float4(-0.5f * ar[0], -0.5f * ar[1], -0.5f * ar[2],  -0.5f * ar[3]);
    orp[1] = make_float4(-0.5f * ar[4], -0.5f * ar[5], -0.5f * ar[6],  -0.5f * ar[7]);
    orp[2] = make_float4(-0.5f * ar[8], -0.5f * ar[9], -0.5f * ar[10], -0.5f * ar[11]);
    oip[0] = make_float4(-0.5f * ai[0], -0.5f * ai[1], -0.5f * ai[2],  -0.5f * ai[3]);
    oip[1] = make_float4(-0.5f * ai[4], -0.5f * ai[5], -0.5f * ai[6],  -0.5f * ai[7]);
    oip[2] = make_float4(-0.5f * ai[8], -0.5f * ai[9], -0.5f * ai[10], -0.5f * ai[11]);
}

extern "C" void kernel_launch(void* const* d_in, const int* in_sizes, int n_in,
                              void* d_out, int out_size, void* d_ws, size_t ws_size,
                              hipStream_t stream) {
    const float* psi_re = (const float*)d_in[0];
    const float* psi_im = (const float*)d_in[1];
    const float* U_re   = (const float*)d_in[2];
    const float* U_im   = (const float*)d_in[3];
    // d_in[4..7] are the projector matrices; hardcoded in-kernel.
    float* out_re = (float*)d_out;
    float* out_im = out_re + (size_t)SITES * 12;

    wilson_dslash_kernel<<<SITES / 128, 128, 0, stream>>>(
        psi_re, psi_im, U_re, U_im, out_re, out_im);
}